// Round 1
// baseline (430.828 us; speedup 1.0000x reference)
//
#include <hip/hip_runtime.h>

#define NN   4096
#define FIN  512
#define FOUT 256
#define ALPHA 0.2f

// ---------------- Kernel 1: wh = h @ W + b  [4096 x 256] ----------------
// grid (4, 64), block 256. 64x64 output tile, K-tile 16, 4x4 regs/thread.
__global__ __launch_bounds__(256) void k_proj(const float* __restrict__ h,
                                              const float* __restrict__ W,
                                              const float* __restrict__ bias,
                                              float* __restrict__ wh) {
    __shared__ float sA[16][68];   // [k][i], padded so float4 rows stay 16B-aligned
    __shared__ float sB[16][64];   // [k][f]
    const int t  = threadIdx.x;
    const int tx = t & 15;         // f-group
    const int ty = t >> 4;         // i-group
    const int i0 = blockIdx.y * 64;
    const int f0 = blockIdx.x * 64;
    const int ka = t & 15, ra = t >> 4;   // A-load ids
    const int fb = t & 63, kb = t >> 6;   // B-load ids
    float acc[4][4] = {};
    for (int k0 = 0; k0 < FIN; k0 += 16) {
        #pragma unroll
        for (int q = 0; q < 4; ++q)
            sA[ka][ra + 16*q] = h[(size_t)(i0 + ra + 16*q) * FIN + k0 + ka];
        #pragma unroll
        for (int q = 0; q < 4; ++q)
            sB[kb + 4*q][fb] = W[(size_t)(k0 + kb + 4*q) * FOUT + f0 + fb];
        __syncthreads();
        #pragma unroll
        for (int kk = 0; kk < 16; ++kk) {
            float4 a4 = *(const float4*)&sA[kk][ty * 4];
            float4 b4 = *(const float4*)&sB[kk][tx * 4];
            acc[0][0] += a4.x*b4.x; acc[0][1] += a4.x*b4.y; acc[0][2] += a4.x*b4.z; acc[0][3] += a4.x*b4.w;
            acc[1][0] += a4.y*b4.x; acc[1][1] += a4.y*b4.y; acc[1][2] += a4.y*b4.z; acc[1][3] += a4.y*b4.w;
            acc[2][0] += a4.z*b4.x; acc[2][1] += a4.z*b4.y; acc[2][2] += a4.z*b4.z; acc[2][3] += a4.z*b4.w;
            acc[3][0] += a4.w*b4.x; acc[3][1] += a4.w*b4.y; acc[3][2] += a4.w*b4.z; acc[3][3] += a4.w*b4.w;
        }
        __syncthreads();
    }
    float4 bb = *(const float4*)&bias[f0 + tx * 4];
    #pragma unroll
    for (int r = 0; r < 4; ++r) {
        float4 o;
        o.x = acc[r][0] + bb.x; o.y = acc[r][1] + bb.y;
        o.z = acc[r][2] + bb.z; o.w = acc[r][3] + bb.w;
        *(float4*)&wh[(size_t)(i0 + ty * 4 + r) * FOUT + f0 + tx * 4] = o;
    }
}

// ------------- Kernel 2: f_src = wh@a1 + a_b, f_dst = wh@a2 -------------
// grid 4096, block 64 (one wave per row).
__global__ __launch_bounds__(64) void k_vec(const float* __restrict__ wh,
                                            const float* __restrict__ a1,
                                            const float* __restrict__ a2,
                                            const float* __restrict__ ab,
                                            float* __restrict__ fs,
                                            float* __restrict__ fd) {
    const int i = blockIdx.x;
    const int t = threadIdx.x;  // 0..63
    float4 w  = ((const float4*)(wh + (size_t)i * FOUT))[t];
    float4 v1 = ((const float4*)a1)[t];
    float4 v2 = ((const float4*)a2)[t];
    float d1 = w.x*v1.x + w.y*v1.y + w.z*v1.z + w.w*v1.w;
    float d2 = w.x*v2.x + w.y*v2.y + w.z*v2.z + w.w*v2.w;
    #pragma unroll
    for (int off = 32; off > 0; off >>= 1) {
        d1 += __shfl_down(d1, off);
        d2 += __shfl_down(d2, off);
    }
    if (t == 0) {
        fs[i] = d1 + ab[0];   // fold the single a_b into the src term
        fd[i] = d2;
    }
}

// ------ Kernel 3: fused mask + exp + weighted-sum + normalize + elu ------
// out[i,:] = elu( (sum_j p_ij * wh[j,:]) / sum_j p_ij )
// p_ij = adj[i,j]>0 ? exp(leakyrelu(fs[i]+fd[j])) : 0   (no max-sub: logits ~ [-6,6])
// grid 256 (16 rows/block), block 256.
#define BI 16
#define TJ 32
__global__ __launch_bounds__(256) void k_attn(const int* __restrict__ adj,
                                              const float* __restrict__ wh,
                                              const float* __restrict__ fs,
                                              const float* __restrict__ fd,
                                              float* __restrict__ out) {
    __shared__ float s_wh[TJ][FOUT];   // 32 KB
    __shared__ float s_p[BI][TJ];      // 2 KB
    __shared__ float s_fs[BI];
    __shared__ float s_sum[BI];
    const int t  = threadIdx.x;
    const int i0 = blockIdx.x * BI;
    // phase-A ids: p computation, 2 values per thread
    const int jl = t & (TJ - 1);       // 0..31
    const int rh = t >> 5;             // 0..7 -> rows rh, rh+8
    // phase-B ids: accumulate, 4 rows x 4 features per thread
    const int x = t & 63;              // float4 feature group
    const int y = t >> 6;              // 0..3 -> rows y+4q

    if (t < BI) s_fs[t] = fs[i0 + t];
    float acc[4][4] = {};              // [q][c], row = y + 4q
    float psum0 = 0.f, psum1 = 0.f;

    for (int j0 = 0; j0 < NN; j0 += TJ) {
        __syncthreads();               // protects s_p/s_wh from previous readers (+ s_fs on iter 0)
        // ---- phase A: p values for this tile ----
        float fdj = fd[j0 + jl];
        {
            int   av = adj[(size_t)(i0 + rh) * NN + j0 + jl];
            float l  = s_fs[rh] + fdj;
            l = l > 0.f ? l : ALPHA * l;
            float p = (av > 0) ? __expf(l) : 0.f;
            s_p[rh][jl] = p; psum0 += p;

            int   av2 = adj[(size_t)(i0 + rh + 8) * NN + j0 + jl];
            float l2  = s_fs[rh + 8] + fdj;
            l2 = l2 > 0.f ? l2 : ALPHA * l2;
            float p2 = (av2 > 0) ? __expf(l2) : 0.f;
            s_p[rh + 8][jl] = p2; psum1 += p2;
        }
        // ---- stage wh tile: 32 rows x 256 f ----
        #pragma unroll
        for (int q = 0; q < 8; ++q) {
            int row = (t >> 6) + 4 * q;
            ((float4*)s_wh[row])[x] = ((const float4*)(wh + (size_t)(j0 + row) * FOUT))[x];
        }
        __syncthreads();
        // ---- phase B: acc += p * wh ----
        #pragma unroll
        for (int jj = 0; jj < TJ; ++jj) {
            float4 w = ((const float4*)s_wh[jj])[x];
            float p0 = s_p[y     ][jj];
            float p1 = s_p[y + 4 ][jj];
            float p2 = s_p[y + 8 ][jj];
            float p3 = s_p[y + 12][jj];
            acc[0][0] += p0*w.x; acc[0][1] += p0*w.y; acc[0][2] += p0*w.z; acc[0][3] += p0*w.w;
            acc[1][0] += p1*w.x; acc[1][1] += p1*w.y; acc[1][2] += p1*w.z; acc[1][3] += p1*w.w;
            acc[2][0] += p2*w.x; acc[2][1] += p2*w.y; acc[2][2] += p2*w.z; acc[2][3] += p2*w.w;
            acc[3][0] += p3*w.x; acc[3][1] += p3*w.y; acc[3][2] += p3*w.z; acc[3][3] += p3*w.w;
        }
    }
    // ---- reduce row sums (reuse s_p) ----
    __syncthreads();
    s_p[rh][jl]     = psum0;
    s_p[rh + 8][jl] = psum1;
    __syncthreads();
    if (t < BI) {
        float s = 0.f;
        #pragma unroll
        for (int jj = 0; jj < TJ; ++jj) s += s_p[t][jj];
        s_sum[t] = s;
    }
    __syncthreads();
    // ---- normalize + elu + store ----
    #pragma unroll
    for (int q = 0; q < 4; ++q) {
        const int i = i0 + y + 4 * q;
        const float inv = 1.0f / s_sum[y + 4 * q];
        float4 o;
        o.x = acc[q][0] * inv; o.y = acc[q][1] * inv;
        o.z = acc[q][2] * inv; o.w = acc[q][3] * inv;
        o.x = o.x > 0.f ? o.x : __expf(o.x) - 1.f;
        o.y = o.y > 0.f ? o.y : __expf(o.y) - 1.f;
        o.z = o.z > 0.f ? o.z : __expf(o.z) - 1.f;
        o.w = o.w > 0.f ? o.w : __expf(o.w) - 1.f;
        ((float4*)(out + (size_t)i * FOUT))[x] = o;
    }
}

extern "C" void kernel_launch(void* const* d_in, const int* in_sizes, int n_in,
                              void* d_out, int out_size, void* d_ws, size_t ws_size,
                              hipStream_t stream) {
    const int*   adj = (const int*)  d_in[0];
    const float* h   = (const float*)d_in[1];
    const float* W   = (const float*)d_in[2];
    const float* b   = (const float*)d_in[3];
    const float* a1  = (const float*)d_in[4];
    const float* a2  = (const float*)d_in[5];
    const float* ab  = (const float*)d_in[6];
    float* out = (float*)d_out;

    // workspace layout: wh [4096*256 f32] | fs [4096] | fd [4096]  (~4.23 MB)
    float* wh = (float*)d_ws;
    float* fs = wh + (size_t)NN * FOUT;
    float* fd = fs + NN;

    k_proj<<<dim3(FOUT / 64, NN / 64), 256, 0, stream>>>(h, W, b, wh);
    k_vec <<<NN, 64, 0, stream>>>(wh, a1, a2, ab, fs, fd);
    k_attn<<<NN / BI, 256, 0, stream>>>(adj, wh, fs, fd, out);
}

// Round 2
// 312.680 us; speedup vs baseline: 1.3779x; 1.3779x over previous
//
#include <hip/hip_runtime.h>

#define NN   4096
#define FIN  512
#define FOUT 256
#define ALPHA 0.2f

// ---------------- Kernel 1: wh = h @ W + b  [4096 x 256] ----------------
// 32x64 output tile, K-tile 32, grid (4,128)=512 blocks -> 2 blocks/CU.
__global__ __launch_bounds__(256) void k_proj(const float* __restrict__ h,
                                              const float* __restrict__ W,
                                              const float* __restrict__ bias,
                                              float* __restrict__ wh) {
    __shared__ float sA[32][34];   // [k][i], +2 pad (8B-aligned float2 rows)
    __shared__ float sB[32][64];   // [k][f]
    const int t  = threadIdx.x;
    const int tx = t & 15;         // f-group (4 floats)
    const int ty = t >> 4;         // i-group (2 rows)
    const int i0 = blockIdx.y * 32;
    const int f0 = blockIdx.x * 64;
    const int ka = t & 31, ia = t >> 5;   // A-load ids (8 rows/pass)
    const int fb = t & 63, kb = t >> 6;   // B-load ids (4 rows/pass)
    float acc[2][4] = {};
    for (int k0 = 0; k0 < FIN; k0 += 32) {
        #pragma unroll
        for (int q = 0; q < 4; ++q)
            sA[ka][ia + 8*q] = h[(size_t)(i0 + ia + 8*q) * FIN + k0 + ka];
        #pragma unroll
        for (int q = 0; q < 8; ++q)
            sB[kb + 4*q][fb] = W[(size_t)(k0 + kb + 4*q) * FOUT + f0 + fb];
        __syncthreads();
        #pragma unroll
        for (int kk = 0; kk < 32; ++kk) {
            float2 a2 = *(const float2*)&sA[kk][ty * 2];
            float4 b4 = *(const float4*)&sB[kk][tx * 4];
            acc[0][0] += a2.x*b4.x; acc[0][1] += a2.x*b4.y; acc[0][2] += a2.x*b4.z; acc[0][3] += a2.x*b4.w;
            acc[1][0] += a2.y*b4.x; acc[1][1] += a2.y*b4.y; acc[1][2] += a2.y*b4.z; acc[1][3] += a2.y*b4.w;
        }
        __syncthreads();
    }
    float4 bb = *(const float4*)&bias[f0 + tx * 4];
    #pragma unroll
    for (int r = 0; r < 2; ++r) {
        float4 o;
        o.x = acc[r][0] + bb.x; o.y = acc[r][1] + bb.y;
        o.z = acc[r][2] + bb.z; o.w = acc[r][3] + bb.w;
        *(float4*)&wh[(size_t)(i0 + ty * 2 + r) * FOUT + f0 + tx * 4] = o;
    }
}

// ------------- Kernel 2: f_src = wh@a1 + a_b, f_dst = wh@a2 -------------
__global__ __launch_bounds__(64) void k_vec(const float* __restrict__ wh,
                                            const float* __restrict__ a1,
                                            const float* __restrict__ a2,
                                            const float* __restrict__ ab,
                                            float* __restrict__ fs,
                                            float* __restrict__ fd) {
    const int i = blockIdx.x;
    const int t = threadIdx.x;  // 0..63
    float4 w  = ((const float4*)(wh + (size_t)i * FOUT))[t];
    float4 v1 = ((const float4*)a1)[t];
    float4 v2 = ((const float4*)a2)[t];
    float d1 = w.x*v1.x + w.y*v1.y + w.z*v1.z + w.w*v1.w;
    float d2 = w.x*v2.x + w.y*v2.y + w.z*v2.z + w.w*v2.w;
    #pragma unroll
    for (int off = 32; off > 0; off >>= 1) {
        d1 += __shfl_down(d1, off);
        d2 += __shfl_down(d2, off);
    }
    if (t == 0) {
        fs[i] = d1 + ab[0];
        fd[i] = d2;
    }
}

// ------ Kernel 3: j-split fused mask+exp+weighted-sum -> partials ------
// grid (NN/BI, C). Block (i-block b, chunk c) processes j in [c*NN/C, (c+1)*NN/C),
// writes partial acc [BI x FOUT] and partial denom [BI] to workspace.
#define BI 16
#define TJ 32
__global__ __launch_bounds__(256) void k_attn(const int* __restrict__ adj,
                                              const float* __restrict__ wh,
                                              const float* __restrict__ fs,
                                              const float* __restrict__ fd,
                                              float* __restrict__ part,
                                              float* __restrict__ psum) {
    __shared__ float s_wh[TJ][FOUT];     // 32 KB
    __shared__ float s_p[TJ][BI + 4];    // [jj][i], +4 pad keeps 16B align & spreads banks
    __shared__ float s_fs[BI];
    const int t  = threadIdx.x;
    const int i0 = blockIdx.x * BI;
    const int c  = blockIdx.y;
    const int jchunk = NN / gridDim.y;
    const int jbeg = c * jchunk, jend = jbeg + jchunk;
    // phase-A ids
    const int jl = t & (TJ - 1);       // 0..31
    const int rh = t >> 5;             // 0..7 -> rows rh, rh+8
    // phase-B ids: 4 consecutive rows x 4 features per thread
    const int x = t & 63;              // float4 feature group
    const int y = t >> 6;              // 0..3 -> rows 4y..4y+3

    if (t < BI) s_fs[t] = fs[i0 + t];
    float acc[4][4] = {};              // [q][comp], row = 4y+q
    float ps0 = 0.f, ps1 = 0.f;

    for (int j0 = jbeg; j0 < jend; j0 += TJ) {
        __syncthreads();               // protects s_p/s_wh (+ s_fs on iter 0)
        // ---- phase A: p values for this tile ----
        float fdj = fd[j0 + jl];
        {
            int   av = adj[(size_t)(i0 + rh) * NN + j0 + jl];
            float l  = s_fs[rh] + fdj;
            l = l > 0.f ? l : ALPHA * l;
            float p = (av > 0) ? __expf(l) : 0.f;
            s_p[jl][rh] = p; ps0 += p;

            int   av2 = adj[(size_t)(i0 + rh + 8) * NN + j0 + jl];
            float l2  = s_fs[rh + 8] + fdj;
            l2 = l2 > 0.f ? l2 : ALPHA * l2;
            float p2 = (av2 > 0) ? __expf(l2) : 0.f;
            s_p[jl][rh + 8] = p2; ps1 += p2;
        }
        // ---- stage wh tile: 32 rows x 256 f ----
        #pragma unroll
        for (int q = 0; q < 8; ++q) {
            int row = y + 4 * q;
            ((float4*)s_wh[row])[x] = ((const float4*)(wh + (size_t)(j0 + row) * FOUT))[x];
        }
        __syncthreads();
        // ---- phase B: acc += p * wh (float4 p read, broadcast across wave) ----
        #pragma unroll
        for (int jj = 0; jj < TJ; ++jj) {
            float4 w = ((const float4*)s_wh[jj])[x];
            float4 p = *(const float4*)&s_p[jj][4 * y];
            acc[0][0] += p.x*w.x; acc[0][1] += p.x*w.y; acc[0][2] += p.x*w.z; acc[0][3] += p.x*w.w;
            acc[1][0] += p.y*w.x; acc[1][1] += p.y*w.y; acc[1][2] += p.y*w.z; acc[1][3] += p.y*w.w;
            acc[2][0] += p.z*w.x; acc[2][1] += p.z*w.y; acc[2][2] += p.z*w.z; acc[2][3] += p.z*w.w;
            acc[3][0] += p.w*w.x; acc[3][1] += p.w*w.y; acc[3][2] += p.w*w.z; acc[3][3] += p.w*w.w;
        }
    }
    // ---- reduce partial denominators (reuse s_p) ----
    __syncthreads();
    s_p[jl][rh]     = ps0;
    s_p[jl][rh + 8] = ps1;
    __syncthreads();
    if (t < BI) {
        float s = 0.f;
        #pragma unroll
        for (int jj = 0; jj < TJ; ++jj) s += s_p[jj][t];
        psum[(size_t)c * NN + i0 + t] = s;
    }
    // ---- store partial sums ----
    float* pc = part + ((size_t)c * NN + i0) * FOUT;
    #pragma unroll
    for (int q = 0; q < 4; ++q) {
        const int r = 4 * y + q;
        float4 o;
        o.x = acc[q][0]; o.y = acc[q][1]; o.z = acc[q][2]; o.w = acc[q][3];
        ((float4*)(pc + (size_t)r * FOUT))[x] = o;
    }
}

// ------ Kernel 4: combine partials, normalize, elu ------
__global__ __launch_bounds__(256) void k_comb(const float* __restrict__ part,
                                              const float* __restrict__ psum,
                                              float* __restrict__ out, int C) {
    const int g = blockIdx.x * 256 + threadIdx.x;   // float4 index
    const int i = g >> 6;                            // row
    const size_t s4 = (size_t)NN * FOUT / 4;
    float4 a = ((const float4*)part)[g];
    float s = psum[i];
    for (int c = 1; c < C; ++c) {
        float4 b = ((const float4*)part)[g + (size_t)c * s4];
        a.x += b.x; a.y += b.y; a.z += b.z; a.w += b.w;
        s += psum[(size_t)c * NN + i];
    }
    const float inv = 1.0f / s;
    a.x *= inv; a.y *= inv; a.z *= inv; a.w *= inv;
    a.x = a.x > 0.f ? a.x : __expf(a.x) - 1.f;
    a.y = a.y > 0.f ? a.y : __expf(a.y) - 1.f;
    a.z = a.z > 0.f ? a.z : __expf(a.z) - 1.f;
    a.w = a.w > 0.f ? a.w : __expf(a.w) - 1.f;
    ((float4*)out)[g] = a;
}

extern "C" void kernel_launch(void* const* d_in, const int* in_sizes, int n_in,
                              void* d_out, int out_size, void* d_ws, size_t ws_size,
                              hipStream_t stream) {
    const int*   adj = (const int*)  d_in[0];
    const float* h   = (const float*)d_in[1];
    const float* W   = (const float*)d_in[2];
    const float* b   = (const float*)d_in[3];
    const float* a1  = (const float*)d_in[4];
    const float* a2  = (const float*)d_in[5];
    const float* ab  = (const float*)d_in[6];
    float* out = (float*)d_out;

    // Adaptive j-chunk count based on available scratch (deterministic per session).
    auto need = [](int c) -> size_t {
        return ((size_t)NN * FOUT + 2 * NN          // wh, fs, fd
                + (size_t)c * NN                    // psum
                + (size_t)c * NN * FOUT) * 4;       // part
    };
    int C = 4;
    while (C > 1 && need(C) > ws_size) C >>= 1;

    float* wh   = (float*)d_ws;
    float* fs   = wh + (size_t)NN * FOUT;
    float* fd   = fs + NN;
    float* psum = fd + NN;
    float* part = psum + (size_t)C * NN;

    k_proj<<<dim3(FOUT / 64, NN / 32), 256, 0, stream>>>(h, W, b, wh);
    k_vec <<<NN, 64, 0, stream>>>(wh, a1, a2, ab, fs, fd);
    k_attn<<<dim3(NN / BI, C), 256, 0, stream>>>(adj, wh, fs, fd, part, psum);
    k_comb<<<(NN * FOUT / 4) / 256, 256, 0, stream>>>(part, psum, out, C);
}

// Round 3
// 180.624 us; speedup vs baseline: 2.3852x; 1.7311x over previous
//
#include <hip/hip_runtime.h>

#define NN   4096
#define FIN  512
#define FOUT 256
#define ALPHA 0.2f

typedef __attribute__((ext_vector_type(8))) short short8;
typedef __attribute__((ext_vector_type(4))) float f32x4;
typedef unsigned short u16;

__device__ __forceinline__ u16 f2bf(float x) {   // round-to-nearest-even
    union { float f; unsigned u; } v; v.f = x;
    unsigned r = v.u + 0x7FFF + ((v.u >> 16) & 1);
    return (u16)(r >> 16);
}

// ---------------- Kernel 0: Wt[f][k] bf16 = transpose(W [k][f] fp32) ----------------
// grid (FOUT/64, FIN/64) = (4,8), block 256.
__global__ __launch_bounds__(256) void k_wt(const float* __restrict__ W,
                                            u16* __restrict__ Wt) {
    __shared__ float s[64 * 65];
    const int t  = threadIdx.x;
    const int f0 = blockIdx.x * 64;
    const int k0 = blockIdx.y * 64;
    #pragma unroll
    for (int p = 0; p < 4; ++p) {          // read W tile [64k][64f], store s[f][k]
        int q = t + 256 * p, rr = q >> 4, cc = q & 15;
        float4 w4 = *(const float4*)&W[(size_t)(k0 + rr) * FOUT + f0 + cc * 4];
        s[(cc * 4 + 0) * 65 + rr] = w4.x;
        s[(cc * 4 + 1) * 65 + rr] = w4.y;
        s[(cc * 4 + 2) * 65 + rr] = w4.z;
        s[(cc * 4 + 3) * 65 + rr] = w4.w;
    }
    __syncthreads();
    #pragma unroll
    for (int p = 0; p < 4; ++p) {          // write Wt [f][k] bf16, coalesced
        int q = t + 256 * p, f = q >> 4, kg = q & 15;
        ushort4 o;
        o.x = f2bf(s[f * 65 + kg * 4 + 0]);
        o.y = f2bf(s[f * 65 + kg * 4 + 1]);
        o.z = f2bf(s[f * 65 + kg * 4 + 2]);
        o.w = f2bf(s[f * 65 + kg * 4 + 3]);
        *(ushort4*)&Wt[(size_t)(f0 + f) * FIN + k0 + kg * 4] = o;
    }
}

// ---------------- Kernel 1: wh = h @ W + b via MFMA ----------------
// 32x64 tile/block, grid (4,128), block 256 (4 waves, each 16x32 out).
__global__ __launch_bounds__(256) void k_proj(const float* __restrict__ h,
                                              const u16* __restrict__ Wt,
                                              const float* __restrict__ bias,
                                              float* __restrict__ wh) {
    __shared__ u16 s_h[32 * 40];   // [i][k] bf16, stride 40 (2-way banks max)
    __shared__ u16 s_w[64 * 40];   // [f][k] bf16
    const int t  = threadIdx.x;
    const int i0 = blockIdx.y * 32;
    const int f0 = blockIdx.x * 64;
    const int wv = t >> 6, l = t & 63, n = l & 15, quad = l >> 4;
    const int m16 = (wv & 1) * 16, n32 = (wv >> 1) * 32;
    const int hr = t >> 3, hs = t & 7;
    const int wr = t >> 2, wg = t & 3;
    f32x4 acc[2] = {{0.f,0.f,0.f,0.f},{0.f,0.f,0.f,0.f}};
    for (int k0 = 0; k0 < FIN; k0 += 32) {
        __syncthreads();
        float4 hv = *(const float4*)&h[(size_t)(i0 + hr) * FIN + k0 + hs * 4];
        ushort4 hb; hb.x = f2bf(hv.x); hb.y = f2bf(hv.y); hb.z = f2bf(hv.z); hb.w = f2bf(hv.w);
        *(ushort4*)&s_h[hr * 40 + hs * 4] = hb;
        uint4 wvv = *(const uint4*)&Wt[(size_t)(f0 + wr) * FIN + k0 + wg * 8];
        *(uint4*)&s_w[wr * 40 + wg * 8] = wvv;
        __syncthreads();
        short8 a  = *(const short8*)&s_h[(m16 + n) * 40 + quad * 8];
        short8 b0 = *(const short8*)&s_w[(n32 + n) * 40 + quad * 8];
        short8 b1 = *(const short8*)&s_w[(n32 + 16 + n) * 40 + quad * 8];
        acc[0] = __builtin_amdgcn_mfma_f32_16x16x32_bf16(a, b0, acc[0], 0, 0, 0);
        acc[1] = __builtin_amdgcn_mfma_f32_16x16x32_bf16(a, b1, acc[1], 0, 0, 0);
    }
    #pragma unroll
    for (int u = 0; u < 2; ++u) {
        const int f = f0 + n32 + u * 16 + n;
        const float bv = bias[f];
        #pragma unroll
        for (int r = 0; r < 4; ++r) {
            const int i = i0 + m16 + quad * 4 + r;   // D: row=(lane>>4)*4+reg, col=lane&15
            wh[(size_t)i * FOUT + f] = acc[u][r] + bv;
        }
    }
}

// ------------- Kernel 2: f_src = wh@a1 + a_b, f_dst = wh@a2 -------------
__global__ __launch_bounds__(64) void k_vec(const float* __restrict__ wh,
                                            const float* __restrict__ a1,
                                            const float* __restrict__ a2,
                                            const float* __restrict__ ab,
                                            float* __restrict__ fs,
                                            float* __restrict__ fd) {
    const int i = blockIdx.x;
    const int t = threadIdx.x;
    float4 w  = ((const float4*)(wh + (size_t)i * FOUT))[t];
    float4 v1 = ((const float4*)a1)[t];
    float4 v2 = ((const float4*)a2)[t];
    float d1 = w.x*v1.x + w.y*v1.y + w.z*v1.z + w.w*v1.w;
    float d2 = w.x*v2.x + w.y*v2.y + w.z*v2.z + w.w*v2.w;
    #pragma unroll
    for (int off = 32; off > 0; off >>= 1) {
        d1 += __shfl_down(d1, off);
        d2 += __shfl_down(d2, off);
    }
    if (t == 0) { fs[i] = d1 + ab[0]; fd[i] = d2; }
}

// ---- Kernel 3: whT_tiled[j/32][f][j&31] bf16 = transpose(wh) ----
// grid 128, block 256. Output is tile-contiguous: 16 KB per j-tile.
__global__ __launch_bounds__(256) void k_tr(const float* __restrict__ wh,
                                            u16* __restrict__ whT) {
    __shared__ float s[32 * 260];
    const int t = threadIdx.x;
    const int j0 = blockIdx.x * 32;
    #pragma unroll
    for (int p = 0; p < 8; ++p) {
        int q = t + 256 * p, j = q >> 6, f4 = q & 63;
        float4 v = *(const float4*)&wh[(size_t)(j0 + j) * FOUT + f4 * 4];
        *(float4*)&s[j * 260 + f4 * 4] = v;
    }
    __syncthreads();
    u16* dst = whT + (size_t)blockIdx.x * (FOUT * 32);
    #pragma unroll
    for (int p = 0; p < 8; ++p) {
        int q = t + 256 * p, f = q >> 3, jg = q & 7;
        ushort4 o;
        o.x = f2bf(s[(jg * 4 + 0) * 260 + f]);
        o.y = f2bf(s[(jg * 4 + 1) * 260 + f]);
        o.z = f2bf(s[(jg * 4 + 2) * 260 + f]);
        o.w = f2bf(s[(jg * 4 + 3) * 260 + f]);
        *(ushort4*)&dst[f * 32 + jg * 4] = o;
    }
}

// ------ Kernel 4: j-split fused mask+exp + MFMA P@wh -> partials ------
#define BI 16
#define TJ 32
__global__ __launch_bounds__(256) void k_attn(const int* __restrict__ adj,
                                              const u16* __restrict__ whT,
                                              const float* __restrict__ fs,
                                              const float* __restrict__ fd,
                                              float* __restrict__ part,
                                              float* __restrict__ psum) {
    __shared__ u16   s_wt[256 * 40];   // B frags: [f][j] bf16, stride 40
    __shared__ u16   s_p[BI * 40];     // A frags: [i][j] bf16
    __shared__ float s_fs[BI];
    __shared__ float s_red[TJ * BI];
    const int t  = threadIdx.x;
    const int i0 = blockIdx.x * BI;
    const int c  = blockIdx.y;
    const int jchunk = NN / gridDim.y;
    const int jbeg = c * jchunk, jend = jbeg + jchunk;
    const int jl = t & 31, rh = t >> 5;
    const int wv = t >> 6, l = t & 63, n = l & 15, quad = l >> 4;
    if (t < BI) s_fs[t] = fs[i0 + t];
    f32x4 acc[4] = {{0.f,0.f,0.f,0.f},{0.f,0.f,0.f,0.f},{0.f,0.f,0.f,0.f},{0.f,0.f,0.f,0.f}};
    float ps0 = 0.f, ps1 = 0.f;

    for (int j0 = jbeg; j0 < jend; j0 += TJ) {
        __syncthreads();
        // ---- phase A: p = adj ? exp(leakyrelu(fs_i + fd_j)) : 0 ----
        float fdj = fd[j0 + jl];
        {
            int av = adj[(size_t)(i0 + rh) * NN + j0 + jl];
            float lg = s_fs[rh] + fdj;
            lg = lg > 0.f ? lg : ALPHA * lg;
            float p = (av > 0) ? __expf(lg) : 0.f;
            s_p[rh * 40 + jl] = f2bf(p); ps0 += p;
            int av2 = adj[(size_t)(i0 + rh + 8) * NN + j0 + jl];
            float lg2 = s_fs[rh + 8] + fdj;
            lg2 = lg2 > 0.f ? lg2 : ALPHA * lg2;
            float p2 = (av2 > 0) ? __expf(lg2) : 0.f;
            s_p[(rh + 8) * 40 + jl] = f2bf(p2); ps1 += p2;
        }
        // ---- stage whT tile: 16 KB contiguous global -> padded LDS ----
        const uint4* src = (const uint4*)(whT + (size_t)(j0 >> 5) * (FOUT * 32));
        #pragma unroll
        for (int p = 0; p < 4; ++p) {
            int q = t + 256 * p, f = q >> 2, sg = q & 3;
            uint4 v = src[q];
            *(uint4*)&s_wt[f * 40 + sg * 8] = v;
        }
        __syncthreads();
        // ---- MFMA: out[16i x 256f] += P[16x32] @ wh[32x256] ----
        short8 a = *(const short8*)&s_p[n * 40 + quad * 8];
        #pragma unroll
        for (int u = 0; u < 4; ++u) {
            short8 b = *(const short8*)&s_wt[(wv * 64 + u * 16 + n) * 40 + quad * 8];
            acc[u] = __builtin_amdgcn_mfma_f32_16x16x32_bf16(a, b, acc[u], 0, 0, 0);
        }
    }
    // ---- partial denominators ----
    __syncthreads();
    s_red[jl * BI + rh]     = ps0;
    s_red[jl * BI + rh + 8] = ps1;
    __syncthreads();
    if (t < BI) {
        float sm = 0.f;
        #pragma unroll
        for (int jj = 0; jj < TJ; ++jj) sm += s_red[jj * BI + t];
        psum[(size_t)c * NN + i0 + t] = sm;
    }
    // ---- store partial numerators ----
    float* pc = part + ((size_t)c * NN + i0) * FOUT;
    #pragma unroll
    for (int u = 0; u < 4; ++u)
        #pragma unroll
        for (int r = 0; r < 4; ++r)
            pc[(size_t)(quad * 4 + r) * FOUT + wv * 64 + u * 16 + n] = acc[u][r];
}

// ------ Kernel 5: combine partials, normalize, elu ------
__global__ __launch_bounds__(256) void k_comb(const float* __restrict__ part,
                                              const float* __restrict__ psum,
                                              float* __restrict__ out, int C) {
    const int g = blockIdx.x * 256 + threadIdx.x;
    const int i = g >> 6;
    const size_t s4 = (size_t)NN * FOUT / 4;
    float4 a = ((const float4*)part)[g];
    float s = psum[i];
    for (int c = 1; c < C; ++c) {
        float4 b = ((const float4*)part)[g + (size_t)c * s4];
        a.x += b.x; a.y += b.y; a.z += b.z; a.w += b.w;
        s += psum[(size_t)c * NN + i];
    }
    const float inv = 1.0f / s;
    a.x *= inv; a.y *= inv; a.z *= inv; a.w *= inv;
    a.x = a.x > 0.f ? a.x : __expf(a.x) - 1.f;
    a.y = a.y > 0.f ? a.y : __expf(a.y) - 1.f;
    a.z = a.z > 0.f ? a.z : __expf(a.z) - 1.f;
    a.w = a.w > 0.f ? a.w : __expf(a.w) - 1.f;
    ((float4*)out)[g] = a;
}

extern "C" void kernel_launch(void* const* d_in, const int* in_sizes, int n_in,
                              void* d_out, int out_size, void* d_ws, size_t ws_size,
                              hipStream_t stream) {
    const int*   adj = (const int*)  d_in[0];
    const float* h   = (const float*)d_in[1];
    const float* W   = (const float*)d_in[2];
    const float* b   = (const float*)d_in[3];
    const float* a1  = (const float*)d_in[4];
    const float* a2  = (const float*)d_in[5];
    const float* ab  = (const float*)d_in[6];
    float* out = (float*)d_out;

    auto need = [](int c) -> size_t {
        size_t fl = (size_t)NN * FOUT + 2 * NN + (size_t)c * NN + (size_t)c * NN * FOUT;
        size_t us = (size_t)FOUT * FIN + (size_t)NN * FOUT;   // Wt + whT bf16
        return fl * 4 + us * 2;
    };
    int C = 8;
    while (C > 1 && need(C) > ws_size) C >>= 1;

    float* wh   = (float*)d_ws;
    float* fs   = wh + (size_t)NN * FOUT;
    float* fd   = fs + NN;
    float* psum = fd + NN;
    float* part = psum + (size_t)C * NN;
    u16*   Wt   = (u16*)(part + (size_t)C * NN * FOUT);
    u16*   whT  = Wt + (size_t)FOUT * FIN;

    k_wt  <<<dim3(FOUT / 64, FIN / 64), 256, 0, stream>>>(W, Wt);
    k_proj<<<dim3(FOUT / 64, NN / 32), 256, 0, stream>>>(h, Wt, b, wh);
    k_vec <<<NN, 64, 0, stream>>>(wh, a1, a2, ab, fs, fd);
    k_tr  <<<NN / 32, 256, 0, stream>>>(wh, whT);
    k_attn<<<dim3(NN / BI, C), 256, 0, stream>>>(adj, whT, fs, fd, part, psum);
    k_comb<<<(NN * FOUT / 4) / 256, 256, 0, stream>>>(part, psum, out, C);
}

// Round 4
// 151.306 us; speedup vs baseline: 2.8474x; 1.1938x over previous
//
#include <hip/hip_runtime.h>

#define NN   4096
#define FIN  512
#define FOUT 256
#define ALPHA 0.2f

typedef __attribute__((ext_vector_type(8))) short short8;
typedef __attribute__((ext_vector_type(4))) float f32x4;
typedef unsigned short u16;

__device__ __forceinline__ u16 f2bf(float x) {   // round-to-nearest-even
    union { float f; unsigned u; } v; v.f = x;
    unsigned r = v.u + 0x7FFF + ((v.u >> 16) & 1);
    return (u16)(r >> 16);
}

// ---------------- Kernel 0: Wt[f][k] bf16 = transpose(W [k][f] fp32) ----------------
__global__ __launch_bounds__(256) void k_wt(const float* __restrict__ W,
                                            u16* __restrict__ Wt) {
    __shared__ float s[64 * 65];
    const int t  = threadIdx.x;
    const int f0 = blockIdx.x * 64;
    const int k0 = blockIdx.y * 64;
    #pragma unroll
    for (int p = 0; p < 4; ++p) {
        int q = t + 256 * p, rr = q >> 4, cc = q & 15;
        float4 w4 = *(const float4*)&W[(size_t)(k0 + rr) * FOUT + f0 + cc * 4];
        s[(cc * 4 + 0) * 65 + rr] = w4.x;
        s[(cc * 4 + 1) * 65 + rr] = w4.y;
        s[(cc * 4 + 2) * 65 + rr] = w4.z;
        s[(cc * 4 + 3) * 65 + rr] = w4.w;
    }
    __syncthreads();
    #pragma unroll
    for (int p = 0; p < 4; ++p) {
        int q = t + 256 * p, f = q >> 4, kg = q & 15;
        ushort4 o;
        o.x = f2bf(s[f * 65 + kg * 4 + 0]);
        o.y = f2bf(s[f * 65 + kg * 4 + 1]);
        o.z = f2bf(s[f * 65 + kg * 4 + 2]);
        o.w = f2bf(s[f * 65 + kg * 4 + 3]);
        *(ushort4*)&Wt[(size_t)(f0 + f) * FIN + k0 + kg * 4] = o;
    }
}

// ------- Kernel 1: wh = h@W + b (fp32) AND whT bf16 tiles, single barrier -------
// Block: 32 i x 64 f. Stage full 32x512 h slab once; stream Wt B-frags from L2.
// whT layout: [j/32][f][j&31] bf16, tile = FOUT*32 = 8192 elems.
#define HS 520   // u16 LDS row stride (1040 B = 65*16, aligned)
__global__ __launch_bounds__(256) void k_proj(const float* __restrict__ h,
                                              const u16* __restrict__ Wt,
                                              const float* __restrict__ bias,
                                              float* __restrict__ wh,
                                              u16* __restrict__ whT) {
    __shared__ u16 s_h[32 * HS];   // 32 rows x 512 k bf16
    const int t  = threadIdx.x;
    const int f0 = blockIdx.x * 64;
    const int i0 = blockIdx.y * 32;
    // stage h slab: 4096 float4 over 256 threads
    #pragma unroll
    for (int p = 0; p < 16; ++p) {
        int q = t + 256 * p, row = q >> 7, c4 = q & 127;
        float4 v = *(const float4*)&h[(size_t)(i0 + row) * FIN + c4 * 4];
        ushort4 o; o.x = f2bf(v.x); o.y = f2bf(v.y); o.z = f2bf(v.z); o.w = f2bf(v.w);
        *(ushort4*)&s_h[row * HS + c4 * 4] = o;
    }
    __syncthreads();
    const int w = t >> 6, l = t & 63, n = l & 15, quad = l >> 4;
    const int hh = w & 1, fh = w >> 1;
    f32x4 acc[2] = {{0.f,0.f,0.f,0.f},{0.f,0.f,0.f,0.f}};
    #pragma unroll
    for (int k0 = 0; k0 < FIN; k0 += 32) {
        short8 a = *(const short8*)&s_h[(hh * 16 + n) * HS + k0 + quad * 8];
        short8 b0 = *(const short8*)&Wt[(size_t)(f0 + fh * 32 + n) * FIN + k0 + quad * 8];
        short8 b1 = *(const short8*)&Wt[(size_t)(f0 + fh * 32 + 16 + n) * FIN + k0 + quad * 8];
        acc[0] = __builtin_amdgcn_mfma_f32_16x16x32_bf16(a, b0, acc[0], 0, 0, 0);
        acc[1] = __builtin_amdgcn_mfma_f32_16x16x32_bf16(a, b1, acc[1], 0, 0, 0);
    }
    u16* wt_tile = whT + (size_t)(i0 >> 5) * (FOUT * 32);
    #pragma unroll
    for (int u = 0; u < 2; ++u) {
        const int f = f0 + fh * 32 + u * 16 + n;
        const float bv = bias[f];
        #pragma unroll
        for (int r = 0; r < 4; ++r) {
            const int i = i0 + hh * 16 + quad * 4 + r;   // D: row=quad*4+r, col=n
            float val = acc[u][r] + bv;
            wh[(size_t)i * FOUT + f] = val;
            wt_tile[f * 32 + (i - i0)] = f2bf(val);
        }
    }
}

// ------------- Kernel 2: f_src = wh@a1 + a_b, f_dst = wh@a2 -------------
// block 256 = 4 waves, one row per wave; grid 1024.
__global__ __launch_bounds__(256) void k_vec(const float* __restrict__ wh,
                                             const float* __restrict__ a1,
                                             const float* __restrict__ a2,
                                             const float* __restrict__ ab,
                                             float* __restrict__ fs,
                                             float* __restrict__ fd) {
    const int i = blockIdx.x * 4 + (threadIdx.x >> 6);
    const int t = threadIdx.x & 63;
    float4 w  = ((const float4*)(wh + (size_t)i * FOUT))[t];
    float4 v1 = ((const float4*)a1)[t];
    float4 v2 = ((const float4*)a2)[t];
    float d1 = w.x*v1.x + w.y*v1.y + w.z*v1.z + w.w*v1.w;
    float d2 = w.x*v2.x + w.y*v2.y + w.z*v2.z + w.w*v2.w;
    #pragma unroll
    for (int off = 32; off > 0; off >>= 1) {
        d1 += __shfl_down(d1, off);
        d2 += __shfl_down(d2, off);
    }
    if (t == 0) { fs[i] = d1 + ab[0]; fd[i] = d2; }
}

// ------ Kernel 3: fused mask+exp + MFMA P@wh; B-frags direct from L2 ------
// BI=32 i-rows/block, TJ=64 j/iter, C j-chunks. LDS holds only the P tile.
#define BI 32
#define TJ 64
#define PS 72   // u16 stride for s_p (144 B = 9*16, aligned)
__global__ __launch_bounds__(256) void k_attn(const int* __restrict__ adj,
                                              const u16* __restrict__ whT,
                                              const float* __restrict__ fs,
                                              const float* __restrict__ fd,
                                              float* __restrict__ part,
                                              float* __restrict__ psum) {
    __shared__ u16 s_p[BI * PS];       // P tile bf16, [i][j] stride 72
    const int t  = threadIdx.x;
    const int i0 = blockIdx.x * BI;
    const int c  = blockIdx.y;
    const int jchunk = NN / gridDim.y;
    const int jbeg = c * jchunk, jend = jbeg + jchunk;
    // phase-A ids: 8 p-values/thread: rows rh, rh+16; j = jq*4..+4
    const int jq = t & 15, rh = t >> 4;
    const float fs0 = fs[i0 + rh], fs1 = fs[i0 + rh + 16];
    // MFMA ids
    const int w = t >> 6, l = t & 63, n = l & 15, quad = l >> 4;

    f32x4 acc[2][4] = {{{0.f,0.f,0.f,0.f},{0.f,0.f,0.f,0.f},{0.f,0.f,0.f,0.f},{0.f,0.f,0.f,0.f}},
                       {{0.f,0.f,0.f,0.f},{0.f,0.f,0.f,0.f},{0.f,0.f,0.f,0.f},{0.f,0.f,0.f,0.f}}};
    float rs0 = 0.f, rs1 = 0.f;

    // prefetch iter-0 adj/fd
    int4   av0 = *(const int4*)&adj[(size_t)(i0 + rh) * NN + jbeg + jq * 4];
    int4   av1 = *(const int4*)&adj[(size_t)(i0 + rh + 16) * NN + jbeg + jq * 4];
    float4 fdv = *(const float4*)&fd[jbeg + jq * 4];

    for (int j0 = jbeg; j0 < jend; j0 += TJ) {
        // ---- compute p from prefetched regs ----
        ushort4 o0, o1;
        {
            float x, p;
            x = fs0 + fdv.x; x = x > 0.f ? x : ALPHA * x; p = av0.x > 0 ? __expf(x) : 0.f; o0.x = f2bf(p); rs0 += p;
            x = fs0 + fdv.y; x = x > 0.f ? x : ALPHA * x; p = av0.y > 0 ? __expf(x) : 0.f; o0.y = f2bf(p); rs0 += p;
            x = fs0 + fdv.z; x = x > 0.f ? x : ALPHA * x; p = av0.z > 0 ? __expf(x) : 0.f; o0.z = f2bf(p); rs0 += p;
            x = fs0 + fdv.w; x = x > 0.f ? x : ALPHA * x; p = av0.w > 0 ? __expf(x) : 0.f; o0.w = f2bf(p); rs0 += p;
            x = fs1 + fdv.x; x = x > 0.f ? x : ALPHA * x; p = av1.x > 0 ? __expf(x) : 0.f; o1.x = f2bf(p); rs1 += p;
            x = fs1 + fdv.y; x = x > 0.f ? x : ALPHA * x; p = av1.y > 0 ? __expf(x) : 0.f; o1.y = f2bf(p); rs1 += p;
            x = fs1 + fdv.z; x = x > 0.f ? x : ALPHA * x; p = av1.z > 0 ? __expf(x) : 0.f; o1.z = f2bf(p); rs1 += p;
            x = fs1 + fdv.w; x = x > 0.f ? x : ALPHA * x; p = av1.w > 0 ? __expf(x) : 0.f; o1.w = f2bf(p); rs1 += p;
        }
        __syncthreads();   // prev-iter MFMA done reading s_p
        *(ushort4*)&s_p[rh * PS + jq * 4]        = o0;
        *(ushort4*)&s_p[(rh + 16) * PS + jq * 4] = o1;
        // ---- prefetch next iter's adj/fd (off critical path) ----
        if (j0 + TJ < jend) {
            av0 = *(const int4*)&adj[(size_t)(i0 + rh) * NN + j0 + TJ + jq * 4];
            av1 = *(const int4*)&adj[(size_t)(i0 + rh + 16) * NN + j0 + TJ + jq * 4];
            fdv = *(const float4*)&fd[j0 + TJ + jq * 4];
        }
        // ---- B-frags for this iter: direct global (L2-hot whT) ----
        short8 b[2][4];   // [s][u]
        #pragma unroll
        for (int s = 0; s < 2; ++s) {
            const u16* tb = whT + (size_t)((j0 >> 5) + s) * (FOUT * 32) + quad * 8;
            #pragma unroll
            for (int u = 0; u < 4; ++u)
                b[s][u] = *(const short8*)&tb[(w * 64 + u * 16 + n) * 32];
        }
        __syncthreads();   // s_p visible
        // ---- MFMA: 32i x 64f slice per wave ----
        #pragma unroll
        for (int s = 0; s < 2; ++s) {
            short8 a0 = *(const short8*)&s_p[n * PS + s * 32 + quad * 8];
            short8 a1f = *(const short8*)&s_p[(16 + n) * PS + s * 32 + quad * 8];
            #pragma unroll
            for (int u = 0; u < 4; ++u) {
                acc[0][u] = __builtin_amdgcn_mfma_f32_16x16x32_bf16(a0,  b[s][u], acc[0][u], 0, 0, 0);
                acc[1][u] = __builtin_amdgcn_mfma_f32_16x16x32_bf16(a1f, b[s][u], acc[1][u], 0, 0, 0);
            }
        }
    }
    // ---- partial denominators: reduce over the 16 jq lanes ----
    #pragma unroll
    for (int m = 8; m > 0; m >>= 1) {
        rs0 += __shfl_xor(rs0, m);
        rs1 += __shfl_xor(rs1, m);
    }
    if (jq == 0) {
        psum[(size_t)c * NN + i0 + rh]      = rs0;
        psum[(size_t)c * NN + i0 + rh + 16] = rs1;
    }
    // ---- partial numerators ----
    float* pc = part + ((size_t)c * NN + i0) * FOUT;
    #pragma unroll
    for (int hf = 0; hf < 2; ++hf)
        #pragma unroll
        for (int u = 0; u < 4; ++u)
            #pragma unroll
            for (int r = 0; r < 4; ++r)
                pc[(size_t)(hf * 16 + quad * 4 + r) * FOUT + w * 64 + u * 16 + n] = acc[hf][u][r];
}

// ------ Kernel 4: combine partials, normalize, elu ------
__global__ __launch_bounds__(256) void k_fin(const float* __restrict__ part,
                                             const float* __restrict__ psum,
                                             float* __restrict__ out, int C) {
    const int g = blockIdx.x * 256 + threadIdx.x;
    const int i = g >> 6;
    const size_t s4 = (size_t)NN * FOUT / 4;
    float4 a = ((const float4*)part)[g];
    float s = psum[i];
    for (int c = 1; c < C; ++c) {
        float4 bb = ((const float4*)part)[g + (size_t)c * s4];
        a.x += bb.x; a.y += bb.y; a.z += bb.z; a.w += bb.w;
        s += psum[(size_t)c * NN + i];
    }
    const float inv = 1.0f / s;
    a.x *= inv; a.y *= inv; a.z *= inv; a.w *= inv;
    a.x = a.x > 0.f ? a.x : __expf(a.x) - 1.f;
    a.y = a.y > 0.f ? a.y : __expf(a.y) - 1.f;
    a.z = a.z > 0.f ? a.z : __expf(a.z) - 1.f;
    a.w = a.w > 0.f ? a.w : __expf(a.w) - 1.f;
    ((float4*)out)[g] = a;
}

extern "C" void kernel_launch(void* const* d_in, const int* in_sizes, int n_in,
                              void* d_out, int out_size, void* d_ws, size_t ws_size,
                              hipStream_t stream) {
    const int*   adj = (const int*)  d_in[0];
    const float* h   = (const float*)d_in[1];
    const float* W   = (const float*)d_in[2];
    const float* b   = (const float*)d_in[3];
    const float* a1  = (const float*)d_in[4];
    const float* a2  = (const float*)d_in[5];
    const float* ab  = (const float*)d_in[6];
    float* out = (float*)d_out;

    auto need = [](int c) -> size_t {
        size_t fl = (size_t)NN * FOUT + 2 * NN + (size_t)c * NN + (size_t)c * NN * FOUT;
        size_t us = (size_t)FOUT * FIN + (size_t)NN * FOUT;   // Wt + whT bf16
        return fl * 4 + us * 2;
    };
    int C = 4;
    while (C > 1 && need(C) > ws_size) C >>= 1;

    float* wh   = (float*)d_ws;
    float* fs   = wh + (size_t)NN * FOUT;
    float* fd   = fs + NN;
    float* psum = fd + NN;
    float* part = psum + (size_t)C * NN;
    u16*   Wt   = (u16*)(part + (size_t)C * NN * FOUT);
    u16*   whT  = Wt + (size_t)FOUT * FIN;

    k_wt  <<<dim3(FOUT / 64, FIN / 64), 256, 0, stream>>>(W, Wt);
    k_proj<<<dim3(FOUT / 64, NN / 32), 256, 0, stream>>>(h, Wt, b, wh, whT);
    k_vec <<<NN / 4, 256, 0, stream>>>(wh, a1, a2, ab, fs, fd);
    k_attn<<<dim3(NN / BI, C), 256, 0, stream>>>(adj, whT, fs, fd, part, psum);
    k_fin <<<(NN * FOUT / 4) / 256, 256, 0, stream>>>(part, psum, out, C);
}